// Round 6
// baseline (372.974 us; speedup 1.0000x reference)
//
#include <hip/hip_runtime.h>
#include <hip/hip_bf16.h>

typedef _Float16 half8 __attribute__((ext_vector_type(8)));
typedef _Float16 half4 __attribute__((ext_vector_type(4)));
typedef float f32x4 __attribute__((ext_vector_type(4)));

#define KDIM 1024
#define NDIM 1024
#define MROWS 16384   // B*L = 4*4096

#define GLD_LDS16(g, l)                                                  \
  __builtin_amdgcn_global_load_lds(                                      \
      (const __attribute__((address_space(1))) void*)(g),                \
      (__attribute__((address_space(3))) void*)(l), 16, 0, 0)

// ---------------------------------------------------------------------------
// Fused-convert GEMM: Y = act(X @ W^T + bias). X fp32 (or fp16), W fp32.
// Converts to fp16 during LDS staging (T14 reg-staging: global->reg->cvt->
// ds_write), eliminating the separate cvt passes entirely.
// Tile 256x128, BK=64, 8 waves (4M x 2N, 64x64/wave), 2-buf LDS (96 KB).
// Pipeline: loads for tile t+2 issued at iter t, consumed (cvt+write) at
// iter t+1 top via compiler-inserted vmcnt; trailing sync is
// lgkmcnt(0)+s_barrier ONLY, so global loads stay in flight across it.
// LDS XOR-swizzle (slot ^= row&7) applied on BOTH ds_write and ds_read
// (plain writes, so no rule-21 inverse-source needed).
// ACT: 0 = none, 1 = elu(x)+1
// TRANS: 0 = natural Y[row][col]; 1 = per-head transposed fp16 (half4):
//   Y[(b*1024 + col)*4096 + (row&4095)], b = row>>12
// ---------------------------------------------------------------------------
template <int ACT, int TRANS, typename TOUT, typename TA>
__global__ __launch_bounds__(512, 2)
void gemm_fused(const TA* __restrict__ X, const float* __restrict__ W,
                const float* __restrict__ bias, TOUT* __restrict__ Y) {
  constexpr int BM = 256, BN = 128, BK = 64;
  __shared__ _Float16 As[2 * BM * BK];   // 64 KB
  __shared__ _Float16 Bs[2 * BN * BK];   // 32 KB

  const int tid  = threadIdx.x;
  const int lane = tid & 63;
  const int w    = tid >> 6;      // 0..7
  const int wm   = w >> 1;        // 0..3 -> rows wm*64
  const int wn   = w & 1;         // 0..1 -> cols wn*64

  // XCD-aware bijective swizzle (512 blocks, 8 XCDs -> 64 each)
  const int bid = blockIdx.x;
  const int wid = (bid & 7) * 64 + (bid >> 3);
  const int m0  = (wid >> 3) * BM;
  const int n0  = (wid & 7) * BN;

  // staging geometry: 8 threads/row, 8 elems each; thread covers rows
  // sr + p*64 (A: p=0..3, B: p=0..1)
  const int sr = tid >> 3;        // 0..63
  const int sc = (tid & 7) * 8;   // 0..56
  const int wsw = (sc * 2) ^ ((sr & 7) << 4);   // swizzled in-row byte

  const TA*    Abase = X + (size_t)(m0 + sr) * KDIM + sc;
  const float* Bbase = W + (size_t)(n0 + sr) * KDIM + sc;

  float4 aR[8];
  float4 bR[4];
  half8  aH[4];
  f32x4 acc[4][4] = {};

#define ISSUE(T)                                                              \
  {                                                                           \
    const int kk0 = (T) * BK;                                                 \
    if constexpr (sizeof(TA) == 4) {                                          \
      _Pragma("unroll") for (int p = 0; p < 4; ++p) {                         \
        const float* s = (const float*)Abase + (size_t)p * 64 * KDIM + kk0;   \
        aR[2 * p]     = *(const float4*)s;                                    \
        aR[2 * p + 1] = *(const float4*)(s + 4);                              \
      }                                                                       \
    } else {                                                                  \
      _Pragma("unroll") for (int p = 0; p < 4; ++p)                           \
        aH[p] = *(const half8*)((const _Float16*)Abase +                      \
                                (size_t)p * 64 * KDIM + kk0);                 \
    }                                                                         \
    _Pragma("unroll") for (int p = 0; p < 2; ++p) {                           \
      const float* s = Bbase + (size_t)p * 64 * KDIM + kk0;                   \
      bR[2 * p]     = *(const float4*)s;                                      \
      bR[2 * p + 1] = *(const float4*)(s + 4);                                \
    }                                                                         \
  }

#define CVTWR(DB)                                                             \
  {                                                                           \
    _Pragma("unroll") for (int p = 0; p < 4; ++p) {                           \
      half8 h;                                                                \
      if constexpr (sizeof(TA) == 4) {                                        \
        h[0] = (_Float16)aR[2 * p].x;     h[1] = (_Float16)aR[2 * p].y;       \
        h[2] = (_Float16)aR[2 * p].z;     h[3] = (_Float16)aR[2 * p].w;       \
        h[4] = (_Float16)aR[2 * p + 1].x; h[5] = (_Float16)aR[2 * p + 1].y;   \
        h[6] = (_Float16)aR[2 * p + 1].z; h[7] = (_Float16)aR[2 * p + 1].w;   \
      } else {                                                                \
        h = aH[p];                                                            \
      }                                                                       \
      *(half8*)((char*)As + (DB) * 32768 + (sr + p * 64) * 128 + wsw) = h;    \
    }                                                                         \
    _Pragma("unroll") for (int p = 0; p < 2; ++p) {                           \
      half8 h;                                                                \
      h[0] = (_Float16)bR[2 * p].x;     h[1] = (_Float16)bR[2 * p].y;         \
      h[2] = (_Float16)bR[2 * p].z;     h[3] = (_Float16)bR[2 * p].w;         \
      h[4] = (_Float16)bR[2 * p + 1].x; h[5] = (_Float16)bR[2 * p + 1].y;     \
      h[6] = (_Float16)bR[2 * p + 1].z; h[7] = (_Float16)bR[2 * p + 1].w;     \
      *(half8*)((char*)Bs + (DB) * 16384 + (sr + p * 64) * 128 + wsw) = h;    \
    }                                                                         \
  }

  // prologue: tile0 -> LDS buf0; tile1 loads in flight
  ISSUE(0);
  CVTWR(0);                 // compiler inserts vmcnt for aR/bR
  ISSUE(1);
  asm volatile("s_waitcnt lgkmcnt(0)" ::: "memory");
  asm volatile("s_barrier" ::: "memory");

#pragma unroll
  for (int t = 0; t < 16; ++t) {
    if (t < 15) CVTWR((t + 1) & 1);   // consume tile t+1 regs (auto vmcnt)
    if (t < 14) ISSUE(t + 2);         // refill regs, in flight across barrier

    const char* Ab = (const char*)As + (t & 1) * 32768;
    const char* Bb = (const char*)Bs + (t & 1) * 16384;
    half8 afr[4][2], bfr[4][2];
#pragma unroll
    for (int mi = 0; mi < 4; ++mi)
#pragma unroll
      for (int kk = 0; kk < 2; ++kk) {
        int row  = wm * 64 + mi * 16 + (lane & 15);
        int byte = row * 128 + ((lane >> 4) << 4) + kk * 64;
        byte ^= (row & 7) << 4;
        afr[mi][kk] = *(const half8*)(Ab + byte);
      }
#pragma unroll
    for (int ni = 0; ni < 4; ++ni)
#pragma unroll
      for (int kk = 0; kk < 2; ++kk) {
        int row  = wn * 64 + ni * 16 + (lane & 15);
        int byte = row * 128 + ((lane >> 4) << 4) + kk * 64;
        byte ^= (row & 7) << 4;
        bfr[ni][kk] = *(const half8*)(Bb + byte);
      }

    __builtin_amdgcn_s_setprio(1);
#pragma unroll
    for (int kk = 0; kk < 2; ++kk)
#pragma unroll
      for (int mi = 0; mi < 4; ++mi)
#pragma unroll
        for (int ni = 0; ni < 4; ++ni)
          acc[mi][ni] = __builtin_amdgcn_mfma_f32_16x16x32_f16(
              afr[mi][kk], bfr[ni][kk], acc[mi][ni], 0, 0, 0);
    __builtin_amdgcn_s_setprio(0);

    if (t < 15) {
      asm volatile("s_waitcnt lgkmcnt(0)" ::: "memory");  // ds_writes done
      asm volatile("s_barrier" ::: "memory");             // loads stay in flight
    }
  }
#undef ISSUE
#undef CVTWR

  // epilogue: bias + activation + store
#pragma unroll
  for (int ni = 0; ni < 4; ++ni) {
    int col  = n0 + wn * 64 + ni * 16 + (lane & 15);
    float bv = bias[col];
#pragma unroll
    for (int mi = 0; mi < 4; ++mi) {
      int r0 = m0 + wm * 64 + mi * 16 + ((lane >> 4) << 2);
      if constexpr (TRANS) {
        int b  = r0 >> 12;
        int l0 = r0 & 4095;
        half4 hv;
#pragma unroll
        for (int i = 0; i < 4; ++i) {
          float v = acc[mi][ni][i] + bv;
          if constexpr (ACT == 1) v = (v > 0.f) ? (v + 1.f) : __expf(v);
          hv[i] = (_Float16)v;
        }
        *(half4*)((_Float16*)Y + ((size_t)(b * 1024 + col)) * 4096 + l0) = hv;
      } else {
#pragma unroll
        for (int i = 0; i < 4; ++i) {
          float v = acc[mi][ni][i] + bv;
          if constexpr (ACT == 1) v = (v > 0.f) ? (v + 1.f) : __expf(v);
          Y[(size_t)(r0 + i) * NDIM + col] = (TOUT)v;
        }
      }
    }
  }
}

// ---------------------------------------------------------------------------
// kv_mfma: per (bh, chunk): partial C'[e][d] = sum_l VT[e][l]*KT[d][l]
// over l in [ch*512, ch*512+512). A = VT rows + synthesized ones-row
// (m-frag 4 -> Ksum); B = KT rows. fp16 partials.
// ---------------------------------------------------------------------------
__global__ __launch_bounds__(256, 2)
void kv_mfma(const _Float16* __restrict__ KT, const _Float16* __restrict__ VT,
             _Float16* __restrict__ pKV) {
  const int bh = blockIdx.x;      // 0..63
  const int ch = blockIdx.y;      // 0..7
  const int tid  = threadIdx.x;
  const int lane = tid & 63;
  const int w    = tid >> 6;

  __shared__ _Float16 As[64 * 64];  // VT tile
  __shared__ _Float16 Bs[64 * 64];  // KT tile

  const int lr = lane >> 3;
  const int ls = (lane & 7) ^ lr;
  const size_t lbase = (size_t)ch * 512 + ls * 8;
  const _Float16* gA = VT + (size_t)(bh * 64 + w * 16 + lr) * 4096 + lbase;
  const _Float16* gB = KT + (size_t)(bh * 64 + w * 16 + lr) * 4096 + lbase;
  _Float16* ldsA = As + (w * 16) * 64;
  _Float16* ldsB = Bs + (w * 16) * 64;

  half8 aones;
#pragma unroll
  for (int j = 0; j < 8; ++j) aones[j] = (lane & 15) == 0 ? (_Float16)1.0f : (_Float16)0.0f;

  f32x4 acc[5] = {};

  for (int k0 = 0; k0 < 512; k0 += 64) {
    __syncthreads();
#pragma unroll
    for (int c = 0; c < 2; ++c) {
      GLD_LDS16(gA + k0 + (size_t)(c * 8) * 4096, ldsA + c * 8 * 64);
      GLD_LDS16(gB + k0 + (size_t)(c * 8) * 4096, ldsB + c * 8 * 64);
    }
    __syncthreads();

    half8 afr[4][2], bfr[2];
#pragma unroll
    for (int m = 0; m < 4; ++m)
#pragma unroll
      for (int kk = 0; kk < 2; ++kk) {
        int row  = m * 16 + (lane & 15);
        int byte = row * 128 + ((lane >> 4) << 4) + kk * 64;
        byte ^= (row & 7) << 4;
        afr[m][kk] = *(const half8*)((const char*)As + byte);
      }
#pragma unroll
    for (int kk = 0; kk < 2; ++kk) {
      int row  = w * 16 + (lane & 15);
      int byte = row * 128 + ((lane >> 4) << 4) + kk * 64;
      byte ^= (row & 7) << 4;
      bfr[kk] = *(const half8*)((const char*)Bs + byte);
    }
#pragma unroll
    for (int kk = 0; kk < 2; ++kk) {
#pragma unroll
      for (int m = 0; m < 4; ++m)
        acc[m] = __builtin_amdgcn_mfma_f32_16x16x32_f16(afr[m][kk], bfr[kk],
                                                        acc[m], 0, 0, 0);
      acc[4] = __builtin_amdgcn_mfma_f32_16x16x32_f16(aones, bfr[kk],
                                                      acc[4], 0, 0, 0);
    }
  }

  _Float16* outp = pKV + ((size_t)ch * 64 + bh) * 5120;
  const int col = w * 16 + (lane & 15);
#pragma unroll
  for (int m = 0; m < 5; ++m) {
#pragma unroll
    for (int i = 0; i < 4; ++i) {
      int row = m * 16 + ((lane >> 4) << 2) + i;
      outp[row * 64 + col] = (_Float16)acc[m][i];
    }
  }
}

// ---------------------------------------------------------------------------
// Combine 8 fp16 partials -> KVTx fp16 [64 bh][80 rows][64 cols]
// ---------------------------------------------------------------------------
__global__ __launch_bounds__(256)
void kv_combine(const _Float16* __restrict__ pKV, _Float16* __restrict__ KVTx) {
  int g = blockIdx.x * 256 + threadIdx.x;   // 0..327679
  int bh = g / 5120;
  int j  = g - bh * 5120;
  float s = 0.f;
#pragma unroll
  for (int ch = 0; ch < 8; ++ch)
    s += (float)pKV[((size_t)ch * 64 + bh) * 5120 + j];
  KVTx[(size_t)bh * 5120 + j] = (_Float16)s;
}

// ---------------------------------------------------------------------------
// attn: per (mtile, bh): att[m][e] = Z(m) * sum_d Q[m][d]*KV[d][e]
// B tile has 80 rows: 64 KVT rows + Ksum row (64) + 15 zero rows; the 5th
// n-fragment's column 0 yields the Z denominator per row via the same MFMA.
// ---------------------------------------------------------------------------
__global__ __launch_bounds__(256, 2)
void attn_kernel(const _Float16* __restrict__ Qp, const _Float16* __restrict__ KVTx,
                 _Float16* __restrict__ att) {
  const int mt = blockIdx.x;      // 0..31
  const int bh = blockIdx.y;      // 0..63
  const int b  = bh >> 4, h = bh & 15;
  const int tid = threadIdx.x;
  const int lane = tid & 63;
  const int w = tid >> 6;
  const size_t m0 = (size_t)b * 4096 + (size_t)mt * 128;

  __shared__ _Float16 As[128 * 64];
  __shared__ _Float16 Bs[80 * 64];

#pragma unroll
  for (int j = 0; j < 4; ++j) {
    int c    = tid + 256 * j;
    int row  = c >> 3;
    int col8 = (c & 7) << 3;
    int byte = row * 128 + (col8 << 1);
    byte ^= (row & 7) << 4;
    *(half8*)((char*)As + byte) =
        *(const half8*)(Qp + (m0 + row) * KDIM + h * 64 + col8);
  }
  for (int c = tid; c < 640; c += 256) {
    int row  = c >> 3;
    int col8 = (c & 7) << 3;
    int byte = row * 128 + (col8 << 1);
    byte ^= (row & 7) << 4;
    *(half8*)((char*)Bs + byte) = *(const half8*)(KVTx + (size_t)bh * 5120 + c * 8);
  }
  __syncthreads();

  f32x4 acc[2][5] = {};
  half8 afr[2][2], bfr[5][2];
#pragma unroll
  for (int m = 0; m < 2; ++m)
#pragma unroll
    for (int kk = 0; kk < 2; ++kk) {
      int row  = w * 32 + m * 16 + (lane & 15);
      int byte = row * 128 + ((lane >> 4) << 4) + kk * 64;
      byte ^= (row & 7) << 4;
      afr[m][kk] = *(const half8*)((const char*)As + byte);
    }
#pragma unroll
  for (int n = 0; n < 5; ++n)
#pragma unroll
    for (int kk = 0; kk < 2; ++kk) {
      int row  = n * 16 + (lane & 15);
      int byte = row * 128 + ((lane >> 4) << 4) + kk * 64;
      byte ^= (row & 7) << 4;
      bfr[n][kk] = *(const half8*)((const char*)Bs + byte);
    }
#pragma unroll
  for (int kk = 0; kk < 2; ++kk)
#pragma unroll
    for (int m = 0; m < 2; ++m)
#pragma unroll
      for (int n = 0; n < 5; ++n)
        acc[m][n] = __builtin_amdgcn_mfma_f32_16x16x32_f16(afr[m][kk], bfr[n][kk],
                                                           acc[m][n], 0, 0, 0);

#pragma unroll
  for (int m = 0; m < 2; ++m) {
#pragma unroll
    for (int i = 0; i < 4; ++i) {
      float dn = __shfl(acc[m][4][i], lane & 48);
      float z  = 1.f / (dn + 1e-6f);
      size_t row = m0 + w * 32 + m * 16 + ((lane >> 4) << 2) + i;
#pragma unroll
      for (int n = 0; n < 4; ++n) {
        att[row * NDIM + h * 64 + n * 16 + (lane & 15)] =
            (_Float16)(acc[m][n][i] * z);
      }
    }
  }
}

// ---------------------------------------------------------------------------
extern "C" void kernel_launch(void* const* d_in, const int* in_sizes, int n_in,
                              void* d_out, int out_size, void* d_ws, size_t ws_size,
                              hipStream_t stream) {
  const float* q  = (const float*)d_in[0];
  const float* k  = (const float*)d_in[1];
  const float* v  = (const float*)d_in[2];
  const float* wq = (const float*)d_in[3];
  const float* bq = (const float*)d_in[4];
  const float* wk = (const float*)d_in[5];
  const float* bk = (const float*)d_in[6];
  const float* wv = (const float*)d_in[7];
  const float* bv = (const float*)d_in[8];
  const float* wo = (const float*)d_in[9];
  const float* bo = (const float*)d_in[10];
  float* out = (float*)d_out;

  char* ws = (char*)d_ws;
  _Float16* Qp   = (_Float16*)(ws);                    // 33,554,432 B
  _Float16* KT   = (_Float16*)(ws + 33554432);         // 33,554,432 B
  _Float16* VT   = (_Float16*)(ws + 67108864);         // 33,554,432 B
  _Float16* pKVh = (_Float16*)(ws + 100663296);        //  5,242,880 B
  _Float16* KVTx = (_Float16*)(ws + 105906176);        //    655,360 B
  _Float16* att  = KT;                                 // reuse KT after KV built

  const int GBLK = (MROWS / 256) * (NDIM / 128);   // 512 blocks

  // projections with fused fp32->fp16 conversion (no cvt passes)
  gemm_fused<1, 0, _Float16, float><<<GBLK, 512, 0, stream>>>(q, wq, bq, Qp);
  gemm_fused<1, 1, _Float16, float><<<GBLK, 512, 0, stream>>>(k, wk, bk, KT);
  gemm_fused<0, 1, _Float16, float><<<GBLK, 512, 0, stream>>>(v, wv, bv, VT);

  kv_mfma<<<dim3(64, 8), 256, 0, stream>>>(KT, VT, pKVh);
  kv_combine<<<1280, 256, 0, stream>>>(pKVh, KVTx);

  attn_kernel<<<dim3(32, 64), 256, 0, stream>>>(Qp, KVTx, att);

  // output projection: fp16 att x fp32 wo -> fp32 out
  gemm_fused<0, 0, float, _Float16><<<GBLK, 512, 0, stream>>>(att, wo, bo, out);
}

// Round 7
// 263.790 us; speedup vs baseline: 1.4139x; 1.4139x over previous
//
#include <hip/hip_runtime.h>
#include <hip/hip_bf16.h>

typedef _Float16 half8 __attribute__((ext_vector_type(8)));
typedef _Float16 half4 __attribute__((ext_vector_type(4)));
typedef float f32x4 __attribute__((ext_vector_type(4)));

#define KDIM 1024
#define NDIM 1024
#define MROWS 16384   // B*L = 4*4096

#define GLD_LDS16(g, l)                                                  \
  __builtin_amdgcn_global_load_lds(                                      \
      (const __attribute__((address_space(1))) void*)(g),                \
      (__attribute__((address_space(3))) void*)(l), 16, 0, 0)

// ---------------------------------------------------------------------------
// fp32 -> fp16 convert, 8 elems/thread, grid-stride
// ---------------------------------------------------------------------------
__global__ __launch_bounds__(256)
void cvt_f32_to_f16(const float* __restrict__ src, _Float16* __restrict__ dst,
                    int n8) {
  for (int i = blockIdx.x * 256 + threadIdx.x; i < n8; i += gridDim.x * 256) {
    float4 f0 = ((const float4*)src)[2 * i];
    float4 f1 = ((const float4*)src)[2 * i + 1];
    half8 h;
    h[0] = (_Float16)f0.x; h[1] = (_Float16)f0.y;
    h[2] = (_Float16)f0.z; h[3] = (_Float16)f0.w;
    h[4] = (_Float16)f1.x; h[5] = (_Float16)f1.y;
    h[6] = (_Float16)f1.z; h[7] = (_Float16)f1.w;
    ((half8*)dst)[i] = h;
  }
}

// ---------------------------------------------------------------------------
// Deep-pipelined GEMM (round-4 proven structure): Y = act(X @ W^T + bias),
// fp16 in, fp32 accum. Tile 256x128, BK=64, 8 waves (4M x 2N).
// Triple-buffered LDS (144 KB), staging 2 K-tiles ahead via
// global_load_lds(16B), counted s_waitcnt vmcnt(6) + raw s_barrier (tail
// iteration drains vmcnt(0) once). Rule-21 swizzle throughout.
// ACT: 0 = none, 1 = elu(x)+1
// TRANS: 0 = natural; 1 = per-head transposed fp16 (packed half4)
// FUSE: 1 = linear-attention epilogue (Q-projection + attn fused):
//   apply elu+1, round-trip C through LDS to re-fragment as MFMA-A,
//   multiply by the block's 2 KVTx head-panels (staged to LDS), Z-scale,
//   store att fp16 natural. Requires ACT==1, TOUT=_Float16.
// ---------------------------------------------------------------------------
template <int ACT, int TRANS, int FUSE, typename TOUT>
__global__ __launch_bounds__(512, 2)
void gemm_big(const _Float16* __restrict__ X, const _Float16* __restrict__ W,
              const float* __restrict__ bias, TOUT* __restrict__ Y,
              const _Float16* __restrict__ KVTx) {
  constexpr int BM = 256, BN = 128, BK = 64;
  __shared__ _Float16 As[3 * BM * BK];   // 96 KB
  __shared__ _Float16 Bs[3 * BN * BK];   // 48 KB

  const int tid  = threadIdx.x;
  const int lane = tid & 63;
  const int w    = tid >> 6;          // 0..7
  const int wm   = w >> 1;            // 0..3  -> rows wm*64
  const int wn   = w & 1;             // 0..1  -> cols wn*64

  // XCD-aware bijective swizzle (512 blocks, 8 XCDs -> 64 each)
  const int bid = blockIdx.x;
  const int wid = (bid & 7) * 64 + (bid >> 3);
  const int m0  = (wid >> 3) * BM;    // 64 m-blocks
  const int n0  = (wid & 7) * BN;     // 8 n-blocks

  const int lr = lane >> 3;           // row within 8-row group
  const int ls = (lane & 7) ^ lr;     // inverse-swizzled 16B slot

#define STAGE_TILE(kt, bidx)                                                  \
  {                                                                           \
    const int k0s = (kt) * BK;                                                \
    _Float16* la = As + (bidx) * (BM * BK) + w * 512;                         \
    _Float16* lb = Bs + (bidx) * (BN * BK) + w * 512;                         \
    _Pragma("unroll")                                                         \
    for (int j = 0; j < 4; ++j)                                               \
      GLD_LDS16(X + (size_t)(m0 + w * 8 + 64 * j + lr) * KDIM + k0s + ls * 8, \
                la + 4096 * j);                                               \
    _Pragma("unroll")                                                         \
    for (int j = 0; j < 2; ++j)                                               \
      GLD_LDS16(W + (size_t)(n0 + w * 8 + 64 * j + lr) * KDIM + k0s + ls * 8, \
                lb + 4096 * j);                                               \
  }

  f32x4 acc[4][4] = {};

  // prologue: stage tiles 0,1 into buffers 0,1 (12 loads in flight)
  STAGE_TILE(0, 0);
  STAGE_TILE(1, 1);
  asm volatile("s_waitcnt vmcnt(6)" ::: "memory");  // tile 0 landed (own)
  asm volatile("s_barrier" ::: "memory");           // all waves' tile 0 landed

  int bc = 0;
  for (int t = 0; t < 16; ++t) {
    int bs = bc + 2; if (bs >= 3) bs -= 3;
    const char* Ab = (const char*)As + bc * (BM * BK * 2);
    const char* Bb = (const char*)Bs + bc * (BN * BK * 2);

    // fragment ds_reads (buffer bc)
    half8 afr[4][2], bfr[4][2];
#pragma unroll
    for (int mi = 0; mi < 4; ++mi)
#pragma unroll
      for (int kk = 0; kk < 2; ++kk) {
        int row  = wm * 64 + mi * 16 + (lane & 15);
        int byte = row * 128 + ((lane >> 4) << 4) + kk * 64;
        byte ^= (row & 7) << 4;
        afr[mi][kk] = *(const half8*)(Ab + byte);
      }
#pragma unroll
    for (int ni = 0; ni < 4; ++ni)
#pragma unroll
      for (int kk = 0; kk < 2; ++kk) {
        int row  = wn * 64 + ni * 16 + (lane & 15);
        int byte = row * 128 + ((lane >> 4) << 4) + kk * 64;
        byte ^= (row & 7) << 4;
        bfr[ni][kk] = *(const half8*)(Bb + byte);
      }

    // prefetch tile t+2 (in flight across the next barrier)
    if (t < 14) STAGE_TILE(t + 2, bs);

    __builtin_amdgcn_s_setprio(1);
#pragma unroll
    for (int kk = 0; kk < 2; ++kk)
#pragma unroll
      for (int mi = 0; mi < 4; ++mi)
#pragma unroll
        for (int ni = 0; ni < 4; ++ni)
          acc[mi][ni] = __builtin_amdgcn_mfma_f32_16x16x32_f16(
              afr[mi][kk], bfr[ni][kk], acc[mi][ni], 0, 0, 0);
    __builtin_amdgcn_s_setprio(0);

    if (t < 14) {
      asm volatile("s_waitcnt vmcnt(6)" ::: "memory");  // tile t+1 landed (own)
      asm volatile("s_barrier" ::: "memory");
    } else if (t == 14) {
      asm volatile("s_waitcnt vmcnt(0)" ::: "memory");  // tail: tile 15 landed
      asm volatile("s_barrier" ::: "memory");
    }
    ++bc; if (bc == 3) bc = 0;
  }
#undef STAGE_TILE

  if constexpr (FUSE) {
    // ---- fused linear-attention epilogue --------------------------------
    __syncthreads();   // all waves done with staging LDS
    // 1. Q = elu(acc+bias)+1 -> fp16 -> Ct[256 rows][128 cols] (As region),
    //    XOR-swizzled (byte ^= (row&7)<<4 within 256B rows)
    _Float16* Ct = As;
#pragma unroll
    for (int ni = 0; ni < 4; ++ni) {
      int cl   = wn * 64 + ni * 16 + (lane & 15);
      float bv = bias[n0 + cl];
#pragma unroll
      for (int mi = 0; mi < 4; ++mi) {
#pragma unroll
        for (int i = 0; i < 4; ++i) {
          int row = wm * 64 + mi * 16 + ((lane >> 4) << 2) + i;
          float v = acc[mi][ni][i] + bv;
          v = (v > 0.f) ? (v + 1.f) : __expf(v);
          int byte = row * 256 + cl * 2;
          byte ^= (row & 7) << 4;
          *(_Float16*)((char*)Ct + byte) = (_Float16)v;
        }
      }
    }
    // 2. stage this block's 2 KVTx head panels -> Bs region, [2][80][64]
    _Float16* KVs = Bs;
    const int bh0 = ((m0 >> 12) << 4) + (n0 >> 6);
    for (int c = tid; c < 1280; c += 512) {
      int hh  = (c >= 640) ? 1 : 0;
      int cc  = c - hh * 640;
      int row = cc >> 3;
      int co8 = (cc & 7) << 3;
      int byte = hh * 10240 + row * 128 + co8 * 2;
      byte ^= (row & 7) << 4;
      *(half8*)((char*)KVs + byte) =
          *(const half8*)(KVTx + (size_t)(bh0 + hh) * 5120 + cc * 8);
    }
    __syncthreads();
    // 3. att = Q @ KVT (+ Ksum column for Z), per wave: head wn, rows wm*64..
    f32x4 acc2[4][5] = {};
#pragma unroll
    for (int kk = 0; kk < 2; ++kk) {
      half8 afr2[4], bfr2[5];
#pragma unroll
      for (int m = 0; m < 4; ++m) {
        int row  = wm * 64 + m * 16 + (lane & 15);
        int byte = row * 256 + wn * 128 + kk * 64 + ((lane >> 4) << 4);
        byte ^= (row & 7) << 4;
        afr2[m] = *(const half8*)((const char*)Ct + byte);
      }
#pragma unroll
      for (int n = 0; n < 5; ++n) {
        int row  = n * 16 + (lane & 15);
        int byte = wn * 10240 + row * 128 + kk * 64 + ((lane >> 4) << 4);
        byte ^= (row & 7) << 4;
        bfr2[n] = *(const half8*)((const char*)KVs + byte);
      }
#pragma unroll
      for (int m = 0; m < 4; ++m)
#pragma unroll
        for (int n = 0; n < 5; ++n)
          acc2[m][n] = __builtin_amdgcn_mfma_f32_16x16x32_f16(
              afr2[m], bfr2[n], acc2[m][n], 0, 0, 0);
    }
    // 4. Z-scale + store att (natural fp16 layout)
#pragma unroll
    for (int m = 0; m < 4; ++m) {
#pragma unroll
      for (int i = 0; i < 4; ++i) {
        float dn = __shfl(acc2[m][4][i], lane & 48);
        float z  = 1.f / (dn + 1e-6f);
        size_t row = (size_t)m0 + wm * 64 + m * 16 + ((lane >> 4) << 2) + i;
#pragma unroll
        for (int n = 0; n < 4; ++n) {
          int col = n0 + wn * 64 + n * 16 + (lane & 15);
          Y[row * NDIM + col] = (TOUT)(acc2[m][n][i] * z);
        }
      }
    }
    return;
  }

  // ---- standard epilogue: bias + activation + store
#pragma unroll
  for (int ni = 0; ni < 4; ++ni) {
    int col  = n0 + wn * 64 + ni * 16 + (lane & 15);
    float bv = bias[col];
#pragma unroll
    for (int mi = 0; mi < 4; ++mi) {
      int r0 = m0 + wm * 64 + mi * 16 + ((lane >> 4) << 2);
      if constexpr (TRANS) {
        int b  = r0 >> 12;
        int l0 = r0 & 4095;
        half4 hv;
#pragma unroll
        for (int i = 0; i < 4; ++i) {
          float v = acc[mi][ni][i] + bv;
          if constexpr (ACT == 1) v = (v > 0.f) ? (v + 1.f) : __expf(v);
          hv[i] = (_Float16)v;
        }
        *(half4*)((_Float16*)Y + ((size_t)(b * 1024 + col)) * 4096 + l0) = hv;
      } else {
#pragma unroll
        for (int i = 0; i < 4; ++i) {
          float v = acc[mi][ni][i] + bv;
          if constexpr (ACT == 1) v = (v > 0.f) ? (v + 1.f) : __expf(v);
          Y[(size_t)(r0 + i) * NDIM + col] = (TOUT)v;
        }
      }
    }
  }
}

// ---------------------------------------------------------------------------
// kv_mfma: per (bh, chunk): partial C'[e][d] = sum_l VT[e][l]*KT[d][l]
// over l in [ch*512, ch*512+512). A = VT rows + synthesized ones-row
// (m-frag 4 -> Ksum); B = KT rows. fp16 partials.
// ---------------------------------------------------------------------------
__global__ __launch_bounds__(256, 2)
void kv_mfma(const _Float16* __restrict__ KT, const _Float16* __restrict__ VT,
             _Float16* __restrict__ pKV) {
  const int bh = blockIdx.x;      // 0..63
  const int ch = blockIdx.y;      // 0..7
  const int tid  = threadIdx.x;
  const int lane = tid & 63;
  const int w    = tid >> 6;

  __shared__ _Float16 As[64 * 64];  // VT tile
  __shared__ _Float16 Bs[64 * 64];  // KT tile

  const int lr = lane >> 3;
  const int ls = (lane & 7) ^ lr;
  const size_t lbase = (size_t)ch * 512 + ls * 8;
  const _Float16* gA = VT + (size_t)(bh * 64 + w * 16 + lr) * 4096 + lbase;
  const _Float16* gB = KT + (size_t)(bh * 64 + w * 16 + lr) * 4096 + lbase;
  _Float16* ldsA = As + (w * 16) * 64;
  _Float16* ldsB = Bs + (w * 16) * 64;

  half8 aones;
#pragma unroll
  for (int j = 0; j < 8; ++j) aones[j] = (lane & 15) == 0 ? (_Float16)1.0f : (_Float16)0.0f;

  f32x4 acc[5] = {};

  for (int k0 = 0; k0 < 512; k0 += 64) {
    __syncthreads();
#pragma unroll
    for (int c = 0; c < 2; ++c) {
      GLD_LDS16(gA + k0 + (size_t)(c * 8) * 4096, ldsA + c * 8 * 64);
      GLD_LDS16(gB + k0 + (size_t)(c * 8) * 4096, ldsB + c * 8 * 64);
    }
    __syncthreads();

    half8 afr[4][2], bfr[2];
#pragma unroll
    for (int m = 0; m < 4; ++m)
#pragma unroll
      for (int kk = 0; kk < 2; ++kk) {
        int row  = m * 16 + (lane & 15);
        int byte = row * 128 + ((lane >> 4) << 4) + kk * 64;
        byte ^= (row & 7) << 4;
        afr[m][kk] = *(const half8*)((const char*)As + byte);
      }
#pragma unroll
    for (int kk = 0; kk < 2; ++kk) {
      int row  = w * 16 + (lane & 15);
      int byte = row * 128 + ((lane >> 4) << 4) + kk * 64;
      byte ^= (row & 7) << 4;
      bfr[kk] = *(const half8*)((const char*)Bs + byte);
    }
#pragma unroll
    for (int kk = 0; kk < 2; ++kk) {
#pragma unroll
      for (int m = 0; m < 4; ++m)
        acc[m] = __builtin_amdgcn_mfma_f32_16x16x32_f16(afr[m][kk], bfr[kk],
                                                        acc[m], 0, 0, 0);
      acc[4] = __builtin_amdgcn_mfma_f32_16x16x32_f16(aones, bfr[kk],
                                                      acc[4], 0, 0, 0);
    }
  }

  _Float16* outp = pKV + ((size_t)ch * 64 + bh) * 5120;
  const int col = w * 16 + (lane & 15);
#pragma unroll
  for (int m = 0; m < 5; ++m) {
#pragma unroll
    for (int i = 0; i < 4; ++i) {
      int row = m * 16 + ((lane >> 4) << 2) + i;
      outp[row * 64 + col] = (_Float16)acc[m][i];
    }
  }
}

// ---------------------------------------------------------------------------
// Combine 8 fp16 partials -> KVTx fp16 [64 bh][80 rows][64 cols]
// ---------------------------------------------------------------------------
__global__ __launch_bounds__(256)
void kv_combine(const _Float16* __restrict__ pKV, _Float16* __restrict__ KVTx) {
  int g = blockIdx.x * 256 + threadIdx.x;   // 0..327679
  int bh = g / 5120;
  int j  = g - bh * 5120;
  float s = 0.f;
#pragma unroll
  for (int ch = 0; ch < 8; ++ch)
    s += (float)pKV[((size_t)ch * 64 + bh) * 5120 + j];
  KVTx[(size_t)bh * 5120 + j] = (_Float16)s;
}

// ---------------------------------------------------------------------------
extern "C" void kernel_launch(void* const* d_in, const int* in_sizes, int n_in,
                              void* d_out, int out_size, void* d_ws, size_t ws_size,
                              hipStream_t stream) {
  const float* q  = (const float*)d_in[0];
  const float* k  = (const float*)d_in[1];
  const float* v  = (const float*)d_in[2];
  const float* wq = (const float*)d_in[3];
  const float* bq = (const float*)d_in[4];
  const float* wk = (const float*)d_in[5];
  const float* bk = (const float*)d_in[6];
  const float* wv = (const float*)d_in[7];
  const float* bv = (const float*)d_in[8];
  const float* wo = (const float*)d_in[9];
  const float* bo = (const float*)d_in[10];
  float* out = (float*)d_out;

  char* ws = (char*)d_ws;
  _Float16* KT   = (_Float16*)(ws + 33554432);         // 33,554,432 B
  _Float16* VT   = (_Float16*)(ws + 67108864);         // 33,554,432 B
  _Float16* Wh   = (_Float16*)(ws + 100663296);        //  2,097,152 B (reused 4x)
  _Float16* pKVh = (_Float16*)(ws + 102760448);        //  5,242,880 B
  _Float16* KVTx = (_Float16*)(ws + 108003328);        //    655,360 B
  _Float16* att  = KT;                                 // reuse KT after KV built
  _Float16* Xh   = (_Float16*)d_out;                   // fp16 X scratch in d_out

  const int N8_BIG = MROWS * KDIM / 8;   // 2,097,152
  const int N8_W   = KDIM * KDIM / 8;    //   131,072

  const int GBLK = (MROWS / 256) * (NDIM / 128);   // 512 blocks

  // K projection (transposed per-head: KT[bh][d][l])
  cvt_f32_to_f16<<<2048, 256, 0, stream>>>(k, Xh, N8_BIG);
  cvt_f32_to_f16<<<512, 256, 0, stream>>>(wk, Wh, N8_W);
  gemm_big<1, 1, 0, _Float16><<<GBLK, 512, 0, stream>>>(Xh, Wh, bk, KT, nullptr);
  // V projection (transposed per-head: VT[bh][e][l])
  cvt_f32_to_f16<<<2048, 256, 0, stream>>>(v, Xh, N8_BIG);
  cvt_f32_to_f16<<<512, 256, 0, stream>>>(wv, Wh, N8_W);
  gemm_big<0, 1, 0, _Float16><<<GBLK, 512, 0, stream>>>(Xh, Wh, bv, VT, nullptr);

  kv_mfma<<<dim3(64, 8), 256, 0, stream>>>(KT, VT, pKVh);
  kv_combine<<<1280, 256, 0, stream>>>(pKVh, KVTx);

  // Q projection + attention, fused (writes att directly; no Qp buffer)
  cvt_f32_to_f16<<<2048, 256, 0, stream>>>(q, Xh, N8_BIG);
  cvt_f32_to_f16<<<512, 256, 0, stream>>>(wq, Wh, N8_W);
  gemm_big<1, 0, 1, _Float16><<<GBLK, 512, 0, stream>>>(Xh, Wh, bq, att, KVTx);

  // output projection (writes d_out; Xh scratch is dead by now)
  cvt_f32_to_f16<<<512, 256, 0, stream>>>(wo, Wh, N8_W);
  gemm_big<0, 0, 0, float><<<GBLK, 512, 0, stream>>>(att, Wh, bo, out, nullptr);
}

// Round 8
// 252.280 us; speedup vs baseline: 1.4784x; 1.0456x over previous
//
#include <hip/hip_runtime.h>
#include <hip/hip_bf16.h>

typedef _Float16 half8 __attribute__((ext_vector_type(8)));
typedef _Float16 half4 __attribute__((ext_vector_type(4)));
typedef float f32x4 __attribute__((ext_vector_type(4)));

#define KDIM 1024
#define NDIM 1024
#define MROWS 16384   // B*L = 4*4096

#define GLD_LDS16(g, l)                                                  \
  __builtin_amdgcn_global_load_lds(                                      \
      (const __attribute__((address_space(1))) void*)(g),                \
      (__attribute__((address_space(3))) void*)(l), 16, 0, 0)

// ---------------------------------------------------------------------------
// fp32 -> fp16 convert, 8 elems/thread, grid-stride
// ---------------------------------------------------------------------------
__global__ __launch_bounds__(256)
void cvt_f32_to_f16(const float* __restrict__ src, _Float16* __restrict__ dst,
                    int n8) {
  for (int i = blockIdx.x * 256 + threadIdx.x; i < n8; i += gridDim.x * 256) {
    float4 f0 = ((const float4*)src)[2 * i];
    float4 f1 = ((const float4*)src)[2 * i + 1];
    half8 h;
    h[0] = (_Float16)f0.x; h[1] = (_Float16)f0.y;
    h[2] = (_Float16)f0.z; h[3] = (_Float16)f0.w;
    h[4] = (_Float16)f1.x; h[5] = (_Float16)f1.y;
    h[6] = (_Float16)f1.z; h[7] = (_Float16)f1.w;
    ((half8*)dst)[i] = h;
  }
}

// Three-tensor variant: blockIdx.y selects the (src,dst) pair.
__global__ __launch_bounds__(256)
void cvt_multi3(const float* __restrict__ s0, _Float16* __restrict__ d0,
                const float* __restrict__ s1, _Float16* __restrict__ d1,
                const float* __restrict__ s2, _Float16* __restrict__ d2,
                int n8) {
  const float* src = (blockIdx.y == 0) ? s0 : (blockIdx.y == 1) ? s1 : s2;
  _Float16*    dst = (blockIdx.y == 0) ? d0 : (blockIdx.y == 1) ? d1 : d2;
  for (int i = blockIdx.x * 256 + threadIdx.x; i < n8; i += gridDim.x * 256) {
    float4 f0 = ((const float4*)src)[2 * i];
    float4 f1 = ((const float4*)src)[2 * i + 1];
    half8 h;
    h[0] = (_Float16)f0.x; h[1] = (_Float16)f0.y;
    h[2] = (_Float16)f0.z; h[3] = (_Float16)f0.w;
    h[4] = (_Float16)f1.x; h[5] = (_Float16)f1.y;
    h[6] = (_Float16)f1.z; h[7] = (_Float16)f1.w;
    ((half8*)dst)[i] = h;
  }
}

// ---------------------------------------------------------------------------
// CHAMPION (round-4 proven): 256x128, BK=64, 8 waves, 3-buf 144KB,
// counted vmcnt(6), 2-ahead prefetch. 1 block/CU.
// FUSE=1: linear-attention epilogue (Q-projection + attn fused).
// ---------------------------------------------------------------------------
template <int ACT, int TRANS, int FUSE, typename TOUT>
__global__ __launch_bounds__(512, 2)
void gemm_big(const _Float16* __restrict__ X, const _Float16* __restrict__ W,
              const float* __restrict__ bias, TOUT* __restrict__ Y,
              const _Float16* __restrict__ KVTx) {
  constexpr int BM = 256, BN = 128, BK = 64;
  __shared__ _Float16 As[3 * BM * BK];   // 96 KB
  __shared__ _Float16 Bs[3 * BN * BK];   // 48 KB

  const int tid  = threadIdx.x;
  const int lane = tid & 63;
  const int w    = tid >> 6;
  const int wm   = w >> 1;
  const int wn   = w & 1;

  const int bid = blockIdx.x;
  const int wid = (bid & 7) * 64 + (bid >> 3);
  const int m0  = (wid >> 3) * BM;
  const int n0  = (wid & 7) * BN;

  const int lr = lane >> 3;
  const int ls = (lane & 7) ^ lr;

#define STAGE_TILE(kt, bidx)                                                  \
  {                                                                           \
    const int k0s = (kt) * BK;                                                \
    _Float16* la = As + (bidx) * (BM * BK) + w * 512;                         \
    _Float16* lb = Bs + (bidx) * (BN * BK) + w * 512;                         \
    _Pragma("unroll")                                                         \
    for (int j = 0; j < 4; ++j)                                               \
      GLD_LDS16(X + (size_t)(m0 + w * 8 + 64 * j + lr) * KDIM + k0s + ls * 8, \
                la + 4096 * j);                                               \
    _Pragma("unroll")                                                         \
    for (int j = 0; j < 2; ++j)                                               \
      GLD_LDS16(W + (size_t)(n0 + w * 8 + 64 * j + lr) * KDIM + k0s + ls * 8, \
                lb + 4096 * j);                                               \
  }

  f32x4 acc[4][4] = {};

  STAGE_TILE(0, 0);
  STAGE_TILE(1, 1);
  asm volatile("s_waitcnt vmcnt(6)" ::: "memory");
  asm volatile("s_barrier" ::: "memory");

  int bc = 0;
  for (int t = 0; t < 16; ++t) {
    int bs = bc + 2; if (bs >= 3) bs -= 3;
    const char* Ab = (const char*)As + bc * (BM * BK * 2);
    const char* Bb = (const char*)Bs + bc * (BN * BK * 2);

    half8 afr[4][2], bfr[4][2];
#pragma unroll
    for (int mi = 0; mi < 4; ++mi)
#pragma unroll
      for (int kk = 0; kk < 2; ++kk) {
        int row  = wm * 64 + mi * 16 + (lane & 15);
        int byte = row * 128 + ((lane >> 4) << 4) + kk * 64;
        byte ^= (row & 7) << 4;
        afr[mi][kk] = *(const half8*)(Ab + byte);
      }
#pragma unroll
    for (int ni = 0; ni < 4; ++ni)
#pragma unroll
      for (int kk = 0; kk < 2; ++kk) {
        int row  = wn * 64 + ni * 16 + (lane & 15);
        int byte = row * 128 + ((lane >> 4) << 4) + kk * 64;
        byte ^= (row & 7) << 4;
        bfr[ni][kk] = *(const half8*)(Bb + byte);
      }

    if (t < 14) STAGE_TILE(t + 2, bs);

    __builtin_amdgcn_s_setprio(1);
#pragma unroll
    for (int kk = 0; kk < 2; ++kk)
#pragma unroll
      for (int mi = 0; mi < 4; ++mi)
#pragma unroll
        for (int ni = 0; ni < 4; ++ni)
          acc[mi][ni] = __builtin_amdgcn_mfma_f32_16x16x32_f16(
              afr[mi][kk], bfr[ni][kk], acc[mi][ni], 0, 0, 0);
    __builtin_amdgcn_s_setprio(0);

    if (t < 14) {
      asm volatile("s_waitcnt vmcnt(6)" ::: "memory");
      asm volatile("s_barrier" ::: "memory");
    } else if (t == 14) {
      asm volatile("s_waitcnt vmcnt(0)" ::: "memory");
      asm volatile("s_barrier" ::: "memory");
    }
    ++bc; if (bc == 3) bc = 0;
  }
#undef STAGE_TILE

  if constexpr (FUSE) {
    __syncthreads();
    _Float16* Ct = As;
#pragma unroll
    for (int ni = 0; ni < 4; ++ni) {
      int cl   = wn * 64 + ni * 16 + (lane & 15);
      float bv = bias[n0 + cl];
#pragma unroll
      for (int mi = 0; mi < 4; ++mi) {
#pragma unroll
        for (int i = 0; i < 4; ++i) {
          int row = wm * 64 + mi * 16 + ((lane >> 4) << 2) + i;
          float v = acc[mi][ni][i] + bv;
          v = (v > 0.f) ? (v + 1.f) : __expf(v);
          int byte = row * 256 + cl * 2;
          byte ^= (row & 7) << 4;
          *(_Float16*)((char*)Ct + byte) = (_Float16)v;
        }
      }
    }
    _Float16* KVs = Bs;
    const int bh0 = ((m0 >> 12) << 4) + (n0 >> 6);
    for (int c = tid; c < 1280; c += 512) {
      int hh  = (c >= 640) ? 1 : 0;
      int cc  = c - hh * 640;
      int row = cc >> 3;
      int co8 = (cc & 7) << 3;
      int byte = hh * 10240 + row * 128 + co8 * 2;
      byte ^= (row & 7) << 4;
      *(half8*)((char*)KVs + byte) =
          *(const half8*)(KVTx + (size_t)(bh0 + hh) * 5120 + cc * 8);
    }
    __syncthreads();
    f32x4 acc2[4][5] = {};
#pragma unroll
    for (int kk = 0; kk < 2; ++kk) {
      half8 afr2[4], bfr2[5];
#pragma unroll
      for (int m = 0; m < 4; ++m) {
        int row  = wm * 64 + m * 16 + (lane & 15);
        int byte = row * 256 + wn * 128 + kk * 64 + ((lane >> 4) << 4);
        byte ^= (row & 7) << 4;
        afr2[m] = *(const half8*)((const char*)Ct + byte);
      }
#pragma unroll
      for (int n = 0; n < 5; ++n) {
        int row  = n * 16 + (lane & 15);
        int byte = wn * 10240 + row * 128 + kk * 64 + ((lane >> 4) << 4);
        byte ^= (row & 7) << 4;
        bfr2[n] = *(const half8*)((const char*)KVs + byte);
      }
#pragma unroll
      for (int m = 0; m < 4; ++m)
#pragma unroll
        for (int n = 0; n < 5; ++n)
          acc2[m][n] = __builtin_amdgcn_mfma_f32_16x16x32_f16(
              afr2[m], bfr2[n], acc2[m][n], 0, 0, 0);
    }
#pragma unroll
    for (int m = 0; m < 4; ++m) {
#pragma unroll
      for (int i = 0; i < 4; ++i) {
        float dn = __shfl(acc2[m][4][i], lane & 48);
        float z  = 1.f / (dn + 1e-6f);
        size_t row = (size_t)m0 + wm * 64 + m * 16 + ((lane >> 4) << 2) + i;
#pragma unroll
        for (int n = 0; n < 4; ++n) {
          int col = n0 + wn * 64 + n * 16 + (lane & 15);
          Y[row * NDIM + col] = (TOUT)(acc2[m][n][i] * z);
        }
      }
    }
    return;
  }

#pragma unroll
  for (int ni = 0; ni < 4; ++ni) {
    int col  = n0 + wn * 64 + ni * 16 + (lane & 15);
    float bv = bias[col];
#pragma unroll
    for (int mi = 0; mi < 4; ++mi) {
      int r0 = m0 + wm * 64 + mi * 16 + ((lane >> 4) << 2);
      if constexpr (TRANS) {
        int b  = r0 >> 12;
        int l0 = r0 & 4095;
        half4 hv;
#pragma unroll
        for (int i = 0; i < 4; ++i) {
          float v = acc[mi][ni][i] + bv;
          if constexpr (ACT == 1) v = (v > 0.f) ? (v + 1.f) : __expf(v);
          hv[i] = (_Float16)v;
        }
        *(half4*)((_Float16*)Y + ((size_t)(b * 1024 + col)) * 4096 + l0) = hv;
      } else {
#pragma unroll
        for (int i = 0; i < 4; ++i) {
          float v = acc[mi][ni][i] + bv;
          if constexpr (ACT == 1) v = (v > 0.f) ? (v + 1.f) : __expf(v);
          Y[(size_t)(r0 + i) * NDIM + col] = (TOUT)v;
        }
      }
    }
  }
}

// ---------------------------------------------------------------------------
// CHALLENGER: 256x128, BK=32, 8 waves, 3-buf 72KB -> 2 blocks/CU.
// Same counted-vmcnt 2-ahead pipeline (3 loads/wave/tile -> vmcnt(3)).
// LDS rows are 64B (4x16B slots); swizzle slot ^= row&3, realized via
// inverse-swizzled global source (gld_lds dest must be linear, rule 21).
// ---------------------------------------------------------------------------
template <int ACT, int TRANS, typename TOUT>
__global__ __launch_bounds__(512, 4)
void gemm_bk32(const _Float16* __restrict__ X, const _Float16* __restrict__ W,
               const float* __restrict__ bias, TOUT* __restrict__ Y) {
  constexpr int BM = 256, BN = 128, BK = 32;
  __shared__ _Float16 As[3 * BM * BK];   // 48 KB
  __shared__ _Float16 Bs[3 * BN * BK];   // 24 KB

  const int tid  = threadIdx.x;
  const int lane = tid & 63;
  const int w    = tid >> 6;
  const int wm   = w >> 1;
  const int wn   = w & 1;

  const int bid = blockIdx.x;
  const int wid = (bid & 7) * 64 + (bid >> 3);
  const int m0  = (wid >> 3) * BM;
  const int n0  = (wid & 7) * BN;

  // staging: per gld_lds instr, 64 lanes cover 16 rows x 4 slots (16B).
  // lane -> local row lane>>2, slot lane&3; global slot = (lane&3)^(row&3).
  const int lrw = lane >> 2;                     // 0..15
  const int gsl = (lane & 3) ^ (lrw & 3);        // inverse-swizzled slot
  const _Float16* gA = X + (size_t)(m0 + w * 16 + lrw) * KDIM + gsl * 8;
  const _Float16* gB = W + (size_t)(n0 + w * 16 + lrw) * KDIM + gsl * 8;

#define STAGE32(kt, bidx)                                                     \
  {                                                                           \
    const int k0s = (kt) * BK;                                                \
    _Float16* la = As + (bidx) * (BM * BK) + (w * 16) * BK;                   \
    _Float16* lb = Bs + (bidx) * (BN * BK) + (w * 16) * BK;                   \
    GLD_LDS16(gA + k0s, la);                                                  \
    GLD_LDS16(gA + (size_t)128 * KDIM + k0s, la + 128 * BK);                  \
    GLD_LDS16(gB + k0s, lb);                                                  \
  }

  // read swizzle: frag row r = base + (lane&15) (base mult of 16 -> r&3 ==
  // lane&3); byte = r*64 + ((lane>>4)^(lane&3))*16
  const int rsl = ((lane >> 4) ^ (lane & 3)) << 4;

  f32x4 acc[4][4] = {};

  STAGE32(0, 0);
  STAGE32(1, 1);
  asm volatile("s_waitcnt vmcnt(3)" ::: "memory");
  asm volatile("s_barrier" ::: "memory");

  int bc = 0;
  for (int t = 0; t < 32; ++t) {
    int bs = bc + 2; if (bs >= 3) bs -= 3;
    const char* Ab = (const char*)As + bc * (BM * BK * 2);
    const char* Bb = (const char*)Bs + bc * (BN * BK * 2);

    half8 afr[4], bfr[4];
#pragma unroll
    for (int mi = 0; mi < 4; ++mi) {
      int row = wm * 64 + mi * 16 + (lane & 15);
      afr[mi] = *(const half8*)(Ab + row * 64 + rsl);
    }
#pragma unroll
    for (int ni = 0; ni < 4; ++ni) {
      int row = wn * 64 + ni * 16 + (lane & 15);
      bfr[ni] = *(const half8*)(Bb + row * 64 + rsl);
    }

    if (t < 30) STAGE32(t + 2, bs);

    __builtin_amdgcn_s_setprio(1);
#pragma unroll
    for (int mi = 0; mi < 4; ++mi)
#pragma unroll
      for (int ni = 0; ni < 4; ++ni)
        acc[mi][ni] = __builtin_amdgcn_mfma_f32_16x16x32_f16(
            afr[mi], bfr[ni], acc[mi][ni], 0, 0, 0);
    __builtin_amdgcn_s_setprio(0);

    if (t < 30) {
      asm volatile("s_waitcnt vmcnt(3)" ::: "memory");
      asm volatile("s_barrier" ::: "memory");
    } else if (t == 30) {
      asm volatile("s_waitcnt vmcnt(0)" ::: "memory");
      asm volatile("s_barrier" ::: "memory");
    }
    ++bc; if (bc == 3) bc = 0;
  }
#undef STAGE32

#pragma unroll
  for (int ni = 0; ni < 4; ++ni) {
    int col  = n0 + wn * 64 + ni * 16 + (lane & 15);
    float bv = bias[col];
#pragma unroll
    for (int mi = 0; mi < 4; ++mi) {
      int r0 = m0 + wm * 64 + mi * 16 + ((lane >> 4) << 2);
      if constexpr (TRANS) {
        int b  = r0 >> 12;
        int l0 = r0 & 4095;
        half4 hv;
#pragma unroll
        for (int i = 0; i < 4; ++i) {
          float v = acc[mi][ni][i] + bv;
          if constexpr (ACT == 1) v = (v > 0.f) ? (v + 1.f) : __expf(v);
          hv[i] = (_Float16)v;
        }
        *(half4*)((_Float16*)Y + ((size_t)(b * 1024 + col)) * 4096 + l0) = hv;
      } else {
#pragma unroll
        for (int i = 0; i < 4; ++i) {
          float v = acc[mi][ni][i] + bv;
          if constexpr (ACT == 1) v = (v > 0.f) ? (v + 1.f) : __expf(v);
          Y[(size_t)(r0 + i) * NDIM + col] = (TOUT)v;
        }
      }
    }
  }
}

// ---------------------------------------------------------------------------
// kv_mfma: per (bh, chunk of 1024 l): partial C'[e][d] = sum_l VT[e][l]*KT[d][l]
// A = VT rows + synthesized ones-row (m-frag 4 -> Ksum); B = KT rows.
// ---------------------------------------------------------------------------
__global__ __launch_bounds__(256, 2)
void kv_mfma(const _Float16* __restrict__ KT, const _Float16* __restrict__ VT,
             _Float16* __restrict__ pKV) {
  const int bh = blockIdx.x;      // 0..63
  const int ch = blockIdx.y;      // 0..3
  const int tid  = threadIdx.x;
  const int lane = tid & 63;
  const int w    = tid >> 6;

  __shared__ _Float16 As[64 * 64];
  __shared__ _Float16 Bs[64 * 64];

  const int lr = lane >> 3;
  const int ls = (lane & 7) ^ lr;
  const size_t lbase = (size_t)ch * 1024 + ls * 8;
  const _Float16* gA = VT + (size_t)(bh * 64 + w * 16 + lr) * 4096 + lbase;
  const _Float16* gB = KT + (size_t)(bh * 64 + w * 16 + lr) * 4096 + lbase;
  _Float16* ldsA = As + (w * 16) * 64;
  _Float16* ldsB = Bs + (w * 16) * 64;

  half8 aones;
#pragma unroll
  for (int j = 0; j < 8; ++j) aones[j] = (lane & 15) == 0 ? (_Float16)1.0f : (_Float16)0.0f;

  f32x4 acc[5] = {};

  for (int k0 = 0; k0 < 1024; k0 += 64) {
    __syncthreads();
#pragma unroll
    for (int c = 0; c < 2; ++c) {
      GLD_LDS16(gA + k0 + (size_t)(c * 8) * 4096, ldsA + c * 8 * 64);
      GLD_LDS16(gB + k0 + (size_t)(c * 8) * 4096, ldsB + c * 8 * 64);
    }
    __syncthreads();

    half8 afr[4][2], bfr[2];
#pragma unroll
    for (int m = 0; m < 4; ++m)
#pragma unroll
      for (int kk = 0; kk < 2; ++kk) {
        int row  = m * 16 + (lane & 15);
        int byte = row * 128 + ((lane >> 4) << 4) + kk * 64;
        byte ^= (row & 7) << 4;
        afr[m][kk] = *(const half8*)((const char*)As + byte);
      }
#pragma unroll
    for (int kk = 0; kk < 2; ++kk) {
      int row  = w * 16 + (lane & 15);
      int byte = row * 128 + ((lane >> 4) << 4) + kk * 64;
      byte ^= (row & 7) << 4;
      bfr[kk] = *(const half8*)((const char*)Bs + byte);
    }
#pragma unroll
    for (int kk = 0; kk < 2; ++kk) {
#pragma unroll
      for (int m = 0; m < 4; ++m)
        acc[m] = __builtin_amdgcn_mfma_f32_16x16x32_f16(afr[m][kk], bfr[kk],
                                                        acc[m], 0, 0, 0);
      acc[4] = __builtin_amdgcn_mfma_f32_16x16x32_f16(aones, bfr[kk],
                                                      acc[4], 0, 0, 0);
    }
  }

  _Float16* outp = pKV + ((size_t)ch * 64 + bh) * 5120;
  const int col = w * 16 + (lane & 15);
#pragma unroll
  for (int m = 0; m < 5; ++m) {
#pragma unroll
    for (int i = 0; i < 4; ++i) {
      int row = m * 16 + ((lane >> 4) << 2) + i;
      outp[row * 64 + col] = (_Float16)acc[m][i];
    }
  }
}

// ---------------------------------------------------------------------------
// Combine 4 fp16 partials -> KVTx fp16 [64 bh][80 rows][64 cols]
// ---------------------------------------------------------------------------
__global__ __launch_bounds__(256)
void kv_combine(const _Float16* __restrict__ pKV, _Float16* __restrict__ KVTx) {
  int g = blockIdx.x * 256 + threadIdx.x;   // 0..327679
  int bh = g / 5120;
  int j  = g - bh * 5120;
  float s = 0.f;
#pragma unroll
  for (int ch = 0; ch < 4; ++ch)
    s += (float)pKV[((size_t)ch * 64 + bh) * 5120 + j];
  KVTx[(size_t)bh * 5120 + j] = (_Float16)s;
}

// ---------------------------------------------------------------------------
extern "C" void kernel_launch(void* const* d_in, const int* in_sizes, int n_in,
                              void* d_out, int out_size, void* d_ws, size_t ws_size,
                              hipStream_t stream) {
  const float* q  = (const float*)d_in[0];
  const float* k  = (const float*)d_in[1];
  const float* v  = (const float*)d_in[2];
  const float* wq = (const float*)d_in[3];
  const float* bq = (const float*)d_in[4];
  const float* wk = (const float*)d_in[5];
  const float* bk = (const float*)d_in[6];
  const float* wv = (const float*)d_in[7];
  const float* bv = (const float*)d_in[8];
  const float* wo = (const float*)d_in[9];
  const float* bo = (const float*)d_in[10];
  float* out = (float*)d_out;

  char* ws = (char*)d_ws;
  _Float16* Xq   = (_Float16*)(ws);                    // 0..32MB
  _Float16* KT   = (_Float16*)(ws + 33554432);         // 32..64MB
  _Float16* VT   = (_Float16*)(ws + 67108864);         // 64..96MB
  _Float16* whk  = (_Float16*)(ws + 100663296);        // 2MB (dies after K-gemm)
  _Float16* whv  = (_Float16*)(ws + 102760448);        // 2MB (dies after V-gemm)
  _Float16* whq  = (_Float16*)(ws + 104857600);        // 2MB
  _Float16* pKV  = (_Float16*)(ws + 100663296);        // 2.62MB over dead whk/whv
  _Float16* who  = (_Float16*)(ws + 100663296);        // 2MB over dead pKV
  _Float16* att  = KT;                                 // reuse KT after KV built
  // d_out (64MB) as scratch until the final GEMM:
  _Float16* Xk   = (_Float16*)d_out;                   // 0..32MB of d_out
  _Float16* Xv   = (_Float16*)((char*)d_out + 33554432); // 32..64MB of d_out
  _Float16* KVTx = (_Float16*)((char*)d_out + 33554432); // over dead Xv

  const int N8_BIG = MROWS * KDIM / 8;   // 2,097,152
  const int N8_W   = KDIM * KDIM / 8;    //   131,072

  const int GBLK = (MROWS / 256) * (NDIM / 128);   // 512 blocks

  // all weight converts (wq,wk,wv) in one kernel; all input converts in one
  cvt_multi3<<<dim3(512, 3), 256, 0, stream>>>(wq, whq, wk, whk, wv, whv, N8_W);
  cvt_multi3<<<dim3(2048, 3), 256, 0, stream>>>(k, Xk, v, Xv, q, Xq, N8_BIG);

  // K/V projections: BK32 CHALLENGER (A/B vs champion below, same shape)
  gemm_bk32<1, 1, _Float16><<<GBLK, 512, 0, stream>>>(Xk, whk, bk, KT);
  gemm_bk32<0, 1, _Float16><<<GBLK, 512, 0, stream>>>(Xv, whv, bv, VT);

  kv_mfma<<<dim3(64, 4), 256, 0, stream>>>(KT, VT, pKV);
  kv_combine<<<1280, 256, 0, stream>>>(pKV, KVTx);   // KVTx over dead Xv

  // wo convert into the now-dead pKV slot
  cvt_f32_to_f16<<<512, 256, 0, stream>>>(wo, who, N8_W);

  // Q projection + attention fused (champion structure)
  gemm_big<1, 0, 1, _Float16><<<GBLK, 512, 0, stream>>>(Xq, whq, bq, att, KVTx);

  // output projection (champion structure); overwrites all of d_out
  gemm_big<0, 0, 0, float><<<GBLK, 512, 0, stream>>>(att, who, bo, out, nullptr);
}